// Round 2
// baseline (883.315 us; speedup 1.0000x reference)
//
#include <hip/hip_runtime.h>
#include <hip/hip_bf16.h>
#include <math.h>

#define K_ 4
#define B_ 64
#define S_ 50
#define D_ 256
#define V_ 40000
#define H_ 4
#define DH_ 64
#define NEG_ (-1e9f)
#define SCALE_ 0.125f

typedef __attribute__((ext_vector_type(8))) __bf16 bf16x8v;
typedef __attribute__((ext_vector_type(4))) float f32x4v;

// ---------- helpers ----------
__device__ __forceinline__ float wred_sum(float v) {
#pragma unroll
  for (int off = 32; off > 0; off >>= 1) v += __shfl_xor(v, off, 64);
  return v;
}
__device__ __forceinline__ float wred_max(float v) {
#pragma unroll
  for (int off = 32; off > 0; off >>= 1) v = fmaxf(v, __shfl_xor(v, off, 64));
  return v;
}
__device__ __forceinline__ float softplusf(float x) {
  return (x > 20.f) ? x : log1pf(expf(x));
}
__device__ __forceinline__ float geluf(float x) {
  const float c = 0.7978845608028654f;  // sqrt(2/pi)
  float x3 = x * x * x;
  return 0.5f * x * (1.f + tanhf(c * (x + 0.044715f * x3)));
}
__device__ __forceinline__ float bf2f(unsigned int u) {
  return __uint_as_float(u << 16);
}
__device__ __forceinline__ unsigned short f2bf(float f) {
  unsigned u = __float_as_uint(f);
  return (unsigned short)((u + 0x7fffu + ((u >> 16) & 1u)) >> 16);
}
__device__ __forceinline__ void unp8(uint4 a, float* d) {
  d[0] = bf2f(a.x & 0xffffu); d[1] = bf2f(a.x >> 16);
  d[2] = bf2f(a.y & 0xffffu); d[3] = bf2f(a.y >> 16);
  d[4] = bf2f(a.z & 0xffffu); d[5] = bf2f(a.z >> 16);
  d[6] = bf2f(a.w & 0xffffu); d[7] = bf2f(a.w >> 16);
}

// ---------- weight cast fp32 -> bf16 (one dispatch) ----------
// out layout: wq(262144) wk wv wo w1(1048576) w2(1048576)
__global__ __launch_bounds__(256) void cast_weights(
    const float* __restrict__ wq, const float* __restrict__ wk,
    const float* __restrict__ wv, const float* __restrict__ wo,
    const float* __restrict__ w1, const float* __restrict__ w2,
    unsigned short* __restrict__ out) {
  long i4 = ((long)blockIdx.x * 256 + threadIdx.x) * 4;
  const float* src; long off;
  if (i4 < 262144) { src = wq; off = i4; }
  else if (i4 < 524288) { src = wk; off = i4 - 262144; }
  else if (i4 < 786432) { src = wv; off = i4 - 524288; }
  else if (i4 < 1048576) { src = wo; off = i4 - 786432; }
  else if (i4 < 2097152) { src = w1; off = i4 - 1048576; }
  else { src = w2; off = i4 - 2097152; }
  float4 v = *(const float4*)(src + off);
  ushort4 o;
  o.x = f2bf(v.x); o.y = f2bf(v.y); o.z = f2bf(v.z); o.w = f2bf(v.w);
  *(ushort4*)(out + i4) = o;
}

// ---------- gating ----------
__global__ __launch_bounds__(256) void gate_kernel(
    const int* __restrict__ ids, const float* __restrict__ emb,
    const float* __restrict__ Wg, const float* __restrict__ Wn,
    const float* __restrict__ eps, float* __restrict__ gates) {
  int w = threadIdx.x >> 6, lane = threadIdx.x & 63;
  int item = blockIdx.x * 4 + w;  // b*S+s
  int b = item / S_, s = item % S_;
  int d0 = lane * 4;
  float4 hs = make_float4(0.f, 0.f, 0.f, 0.f);
#pragma unroll
  for (int k = 0; k < K_; ++k) {
    int id = ids[(k * B_ + b) * S_ + s];
    const float4 e = *(const float4*)(emb + ((long)k * V_ + id) * D_ + d0);
    hs.x += e.x; hs.y += e.y; hs.z += e.z; hs.w += e.w;
  }
  hs.x *= 0.25f; hs.y *= 0.25f; hs.z *= 0.25f; hs.w *= 0.25f;
  float logit[4];
#pragma unroll
  for (int j = 0; j < K_; ++j) {
    float pg = hs.x * Wg[(d0 + 0) * K_ + j] + hs.y * Wg[(d0 + 1) * K_ + j] +
               hs.z * Wg[(d0 + 2) * K_ + j] + hs.w * Wg[(d0 + 3) * K_ + j];
    float pn = hs.x * Wn[(d0 + 0) * K_ + j] + hs.y * Wn[(d0 + 1) * K_ + j] +
               hs.z * Wn[(d0 + 2) * K_ + j] + hs.w * Wn[(d0 + 3) * K_ + j];
    pg = wred_sum(pg);
    pn = wred_sum(pn);
    logit[j] = pg + softplusf(pn) * eps[item * K_ + j];
  }
  if (lane == 0) {
    int i0 = 0; float v0 = logit[0];
    for (int j = 1; j < K_; ++j) if (logit[j] > v0) { v0 = logit[j]; i0 = j; }
    int i1 = -1; float v1 = 0.f;
    for (int j = 0; j < K_; ++j)
      if (j != i0 && (i1 < 0 || logit[j] > v1)) { v1 = logit[j]; i1 = j; }
    float w0 = 1.f / (1.f + expf(v1 - v0));
    float w1 = 1.f - w0;
#pragma unroll
    for (int j = 0; j < K_; ++j)
      gates[item * K_ + j] = (j == i0) ? w0 : ((j == i1) ? w1 : 0.f);
  }
}

// ---------- local aggregator, d-parallel lanes ----------
// grid: (k*B+b)*4 + q ; block q handles a slice of rows
__global__ __launch_bounds__(256) void local_agg2(
    const int* __restrict__ items, const int* __restrict__ adj,
    const int* __restrict__ alias_, const float* __restrict__ emb,
    const float* __restrict__ agg_a, float* __restrict__ h_out) {
  __shared__ float hg[S_][D_];    // row-contiguous lane reads only -> conflict-free
  __shared__ float a_s[4][D_];
  __shared__ int alias_s[S_];
  int blk = blockIdx.x;
  int q = blk & 3, kb = blk >> 2;
  int k = kb / B_, b = kb % B_;
  int t = threadIdx.x;
  for (int f = t; f < S_ * 64; f += 256) {
    int row = f >> 6, c4 = (f & 63) * 4;
    int g = items[kb * S_ + row];
    *(float4*)&hg[row][c4] = *(const float4*)(emb + ((long)k * V_ + g) * D_ + c4);
  }
  {
    int r = t >> 6, c4 = (t & 63) * 4;
    *(float4*)&a_s[r][c4] = *(const float4*)(agg_a + ((long)k * 4 + r) * D_ + c4);
  }
  if (t < S_) alias_s[t] = alias_[b * S_ + t];
  __syncthreads();
  int w = t >> 6, lane = t & 63;
  // preload relation vectors into registers (lane = d within chunk)
  float a10 = a_s[0][lane], a11 = a_s[0][64 + lane], a12 = a_s[0][128 + lane], a13 = a_s[0][192 + lane];
  float a20 = a_s[1][lane], a21 = a_s[1][64 + lane], a22 = a_s[1][128 + lane], a23 = a_s[1][192 + lane];
  float a30 = a_s[2][lane], a31 = a_s[2][64 + lane], a32 = a_s[2][128 + lane], a33 = a_s[2][192 + lane];
  float a40 = a_s[3][lane], a41 = a_s[3][64 + lane], a42 = a_s[3][128 + lane], a43 = a_s[3][192 + lane];
  int r0 = q * 13 - (q == 3 ? 1 : 0);       // 0,13,26,38
  int cnt = (q < 2) ? 13 : 12;
  for (int i = r0 + w; i < r0 + cnt; i += 4) {
    int adjv = 0;
    if (lane < S_) adjv = adj[((long)b * S_ + i) * S_ + lane];
    float hi0 = hg[i][lane], hi1 = hg[i][64 + lane], hi2 = hg[i][128 + lane], hi3 = hg[i][192 + lane];
    float ev = (lane < S_) ? NEG_ : -INFINITY;
    for (int j = 0; j < S_; ++j) {
      int r = __shfl(adjv, j, 64);    // wave-uniform
      if (r) {
        float hj0 = hg[j][lane], hj1 = hg[j][64 + lane];
        float hj2 = hg[j][128 + lane], hj3 = hg[j][192 + lane];
        float p0 = hi0 * hj0, p1 = hi1 * hj1, p2 = hi2 * hj2, p3 = hi3 * hj3;
        float tv;
        if (r == 1)      tv = fmaf(p0, a10, fmaf(p1, a11, fmaf(p2, a12, p3 * a13)));
        else if (r == 2) tv = fmaf(p0, a20, fmaf(p1, a21, fmaf(p2, a22, p3 * a23)));
        else if (r == 3) tv = fmaf(p0, a30, fmaf(p1, a31, fmaf(p2, a32, p3 * a33)));
        else             tv = fmaf(p0, a40, fmaf(p1, a41, fmaf(p2, a42, p3 * a43)));
        tv = wred_sum(tv);
        tv = (tv >= 0.f) ? tv : 0.2f * tv;  // leaky relu
        ev = (lane == j) ? tv : ev;
      }
    }
    float m = wred_max(ev);
    float p = expf(ev - m);        // pads (-inf) -> 0; NEG rows -> uniform, matches ref
    float ssum = wred_sum(p);
    float alpha = p / ssum;
    float acc0 = 0, acc1 = 0, acc2 = 0, acc3 = 0;
    for (int j = 0; j < S_; ++j) {
      float aj = __shfl(alpha, j, 64);
      if (aj != 0.f) {
        acc0 = fmaf(aj, hg[j][lane], acc0);
        acc1 = fmaf(aj, hg[j][64 + lane], acc1);
        acc2 = fmaf(aj, hg[j][128 + lane], acc2);
        acc3 = fmaf(aj, hg[j][192 + lane], acc3);
      }
    }
    for (int s = 0; s < S_; ++s) {
      if (alias_s[s] == i) {   // wave-uniform
        float* dst = h_out + ((long)kb * S_ + s) * D_;
        dst[lane] = acc0; dst[64 + lane] = acc1;
        dst[128 + lane] = acc2; dst[192 + lane] = acc3;
      }
    }
  }
}

// ---------- layernorm -> bf16 out (one wave per row) ----------
__global__ __launch_bounds__(256) void ln_bf16(
    const float* __restrict__ x, unsigned short* __restrict__ y,
    const float* __restrict__ g, const float* __restrict__ bta) {
  int w = threadIdx.x >> 6, lane = threadIdx.x & 63;
  long row = (long)blockIdx.x * 4 + w;  // < K*B*S
  int k = (int)(row / (B_ * S_));
  const float4 v = *(const float4*)(x + row * D_ + lane * 4);
  float sum = wred_sum(v.x + v.y + v.z + v.w);
  float sq = wred_sum(v.x * v.x + v.y * v.y + v.z * v.z + v.w * v.w);
  float mean = sum * (1.f / D_);
  float var = sq * (1.f / D_) - mean * mean;
  float rs = rsqrtf(var + 1e-5f);
  const float4 gv = *(const float4*)(g + k * D_ + lane * 4);
  const float4 bv = *(const float4*)(bta + k * D_ + lane * 4);
  ushort4 o;
  o.x = f2bf((v.x - mean) * rs * gv.x + bv.x);
  o.y = f2bf((v.y - mean) * rs * gv.y + bv.y);
  o.z = f2bf((v.z - mean) * rs * gv.z + bv.z);
  o.w = f2bf((v.w - mean) * rs * gv.w + bv.w);
  *(ushort4*)(y + row * D_ + lane * 4) = o;
}

// ---------- bf16 MFMA GEMM: 64x64 tile, BK=32 ----------
// C = act(A@B (+R)) ; A [M,Kd] bf16, B [Kd,N] bf16, batched over z.
// Outputs: Cf fp32 (opt, with opt residual R) and/or Cb bf16.
__global__ __launch_bounds__(256) void bgemm(
    const unsigned short* __restrict__ A, const unsigned short* __restrict__ B,
    long strideA, long strideB, int N, int Kd,
    float* __restrict__ Cf, long strideCf,
    const float* __restrict__ R, long strideR,
    unsigned short* __restrict__ Cb, long strideCb, int act) {
  __shared__ unsigned short sA[64][40];  // [m][k], pad to 40 for bank spread
  __shared__ unsigned short sB[64][40];  // transposed: [n][k]
  int z = blockIdx.z;
  A += (long)z * strideA;
  B += (long)z * strideB;
  int t = threadIdx.x, w = t >> 6, lane = t & 63;
  int row0 = blockIdx.x * 64, col0 = blockIdx.y * 64;
  f32x4v acc[4];
#pragma unroll
  for (int nt = 0; nt < 4; ++nt) acc[nt] = (f32x4v){0.f, 0.f, 0.f, 0.f};
  int ar = t >> 2, ac = (t & 3) * 8;   // A stage: 64 rows x 32 k
  int bk = t >> 3, bn = (t & 7) * 8;   // B stage: 32 k x 64 n
  int m16 = lane & 15, kg = (lane >> 4) * 8;
  for (int k0 = 0; k0 < Kd; k0 += 32) {
    uint4 av = *(const uint4*)(A + (long)(row0 + ar) * Kd + k0 + ac);
    uint4 bv = *(const uint4*)(B + (long)(k0 + bk) * N + col0 + bn);
    __syncthreads();  // protect previous iteration's LDS reads
    *(uint4*)&sA[ar][ac] = av;
    sB[bn + 0][bk] = (unsigned short)(bv.x & 0xffffu);
    sB[bn + 1][bk] = (unsigned short)(bv.x >> 16);
    sB[bn + 2][bk] = (unsigned short)(bv.y & 0xffffu);
    sB[bn + 3][bk] = (unsigned short)(bv.y >> 16);
    sB[bn + 4][bk] = (unsigned short)(bv.z & 0xffffu);
    sB[bn + 5][bk] = (unsigned short)(bv.z >> 16);
    sB[bn + 6][bk] = (unsigned short)(bv.w & 0xffffu);
    sB[bn + 7][bk] = (unsigned short)(bv.w >> 16);
    __syncthreads();
    bf16x8v af = *(const bf16x8v*)&sA[w * 16 + m16][kg];
#pragma unroll
    for (int nt = 0; nt < 4; ++nt) {
      bf16x8v bf = *(const bf16x8v*)&sB[nt * 16 + m16][kg];
      acc[nt] = __builtin_amdgcn_mfma_f32_16x16x32_bf16(af, bf, acc[nt], 0, 0, 0);
    }
  }
  // epilogue: C/D layout col=lane&15, row=(lane>>4)*4+reg  [m89/m91]
  int rbase = row0 + w * 16 + (lane >> 4) * 4;
  int cb = lane & 15;
#pragma unroll
  for (int nt = 0; nt < 4; ++nt) {
#pragma unroll
    for (int i2 = 0; i2 < 4; ++i2) {
      long off = (long)(rbase + i2) * N + col0 + nt * 16 + cb;
      float vv = acc[nt][i2];
      if (R) vv += R[(long)z * strideR + off];
      if (act == 1) vv = geluf(vv);
      if (Cf) Cf[(long)z * strideCf + off] = vv;
      if (Cb) Cb[(long)z * strideCb + off] = f2bf(vv);
    }
  }
}

// ---------- causal MHA core: block per (k,b,head), bf16 in/out ----------
__global__ __launch_bounds__(256) void attn_kernel(
    const unsigned short* __restrict__ q, const unsigned short* __restrict__ kx,
    const unsigned short* __restrict__ v, unsigned short* __restrict__ o) {
  __shared__ float qs[S_][65], ks[S_][65], vs[S_][65];
  int idx = blockIdx.x;
  int h = idx & 3;       // H_=4
  int kb = idx >> 2;     // k*B+b
  long base = ((long)kb * S_) * D_ + h * DH_;
  int t = threadIdx.x;
  for (int f = t; f < S_ * 8; f += 256) {
    int row = f >> 3, c8 = (f & 7) * 8;
    long g = base + (long)row * D_ + c8;
    unp8(*(const uint4*)(q + g), &qs[row][c8]);
    unp8(*(const uint4*)(kx + g), &ks[row][c8]);
    unp8(*(const uint4*)(v + g), &vs[row][c8]);
  }
  __syncthreads();
  int w = t >> 6, lane = t & 63;
  for (int i = w; i < S_; i += 4) {
    int jj = (lane < S_) ? lane : 0;
    float dot = 0.f;
#pragma unroll
    for (int d = 0; d < DH_; ++d) dot = fmaf(qs[i][d], ks[jj][d], dot);
    float val = (lane <= i) ? dot * SCALE_ : ((lane < S_) ? NEG_ : -INFINITY);
    float m = wred_max(val);
    float p = expf(val - m);
    float ssum = wred_sum(p);
    float pr = p / ssum;
    float acc = 0.f;
    for (int j = 0; j <= i; ++j)
      acc = fmaf(__shfl(pr, j, 64), vs[j][lane], acc);
    o[base + (long)i * D_ + lane] = f2bf(acc);
  }
}

// ---------- gated combine ----------
__global__ __launch_bounds__(256) void combine_kernel(
    const float* __restrict__ gates, const float* __restrict__ h,
    float* __restrict__ out) {
  int w = threadIdx.x >> 6, lane = threadIdx.x & 63;
  int item = blockIdx.x * 4 + w;  // b*S+s
  float g0 = gates[item * 4 + 0], g1 = gates[item * 4 + 1];
  float g2 = gates[item * 4 + 2], g3 = gates[item * 4 + 3];
  long off = (long)item * D_ + lane * 4;
  const long PK = (long)B_ * S_ * D_;
  float4 a = *(const float4*)(h + off);
  float4 b = *(const float4*)(h + PK + off);
  float4 c = *(const float4*)(h + 2 * PK + off);
  float4 d = *(const float4*)(h + 3 * PK + off);
  float4 o;
  o.x = g0 * a.x + g1 * b.x + g2 * c.x + g3 * d.x;
  o.y = g0 * a.y + g1 * b.y + g2 * c.y + g3 * d.y;
  o.z = g0 * a.z + g1 * b.z + g2 * c.z + g3 * d.z;
  o.w = g0 * a.w + g1 * b.w + g2 * c.w + g3 * d.w;
  *(float4*)(out + off) = o;
}

extern "C" void kernel_launch(void* const* d_in, const int* in_sizes, int n_in,
                              void* d_out, int out_size, void* d_ws,
                              size_t ws_size, hipStream_t stream) {
  const int* ids = (const int*)d_in[0];
  const int* items = (const int*)d_in[1];
  const int* adj = (const int*)d_in[2];
  const int* alias = (const int*)d_in[3];
  const float* eps = (const float*)d_in[4];
  const float* emb = (const float*)d_in[5];
  const float* agg_a = (const float*)d_in[6];
  const float* Wq = (const float*)d_in[7];
  const float* Wk = (const float*)d_in[8];
  const float* Wv = (const float*)d_in[9];
  const float* Wo = (const float*)d_in[10];
  const float* ln1g = (const float*)d_in[11];
  const float* ln1b = (const float*)d_in[12];
  const float* W1 = (const float*)d_in[13];
  const float* W2 = (const float*)d_in[14];
  const float* ln2g = (const float*)d_in[15];
  const float* ln2b = (const float*)d_in[16];
  const float* Wg = (const float*)d_in[17];
  const float* Wn = (const float*)d_in[18];
  float* out = (float*)d_out;

  const long BSD = (long)B_ * S_ * D_;  // 819200
  float* ws = (float*)d_ws;
  float* gates = ws;                    // 16384 fp32
  float* hbuf = ws + 16384;             // [K,B,S,D] fp32 residual stream
  // bf16 region (as ushort), 16B-aligned
  unsigned short* ub = (unsigned short*)(ws + 16384 + 4 * BSD);
  unsigned short* xb = ub;              // x / o / y slot [K,B,S,D]
  unsigned short* qb = ub + 3276800;
  unsigned short* kb = qb + 3276800;
  unsigned short* vb = kb + 3276800;
  // tb = FFN hidden [K,B*S,1024] spans qb..vb+extra (q/k/v dead by then)
  unsigned short* tb = qb;              // 13107200 elems (qb,kb,vb + extra)
  unsigned short* wqb = ub + 5 * 3276800;  // weights: 3145728 bf16 total
  unsigned short* wkb = wqb + 262144;
  unsigned short* wvb = wkb + 262144;
  unsigned short* wob = wvb + 262144;
  unsigned short* w1b = wob + 262144;
  unsigned short* w2b = w1b + 1048576;

  const long DD = 65536, DH4 = 262144, T4 = 3276800;

  cast_weights<<<3072, 256, 0, stream>>>(Wq, Wk, Wv, Wo, W1, W2, wqb);
  gate_kernel<<<800, 256, 0, stream>>>(ids, emb, Wg, Wn, eps, gates);
  local_agg2<<<1024, 256, 0, stream>>>(items, adj, alias, emb, agg_a, hbuf);
  ln_bf16<<<3200, 256, 0, stream>>>(hbuf, xb, ln1g, ln1b);
  // QKV projections (bf16 out)
  bgemm<<<dim3(50, 4, 4), 256, 0, stream>>>(xb, wqb, BSD, DD, 256, 256,
      (float*)0, 0, (const float*)0, 0, qb, BSD, 0);
  bgemm<<<dim3(50, 4, 4), 256, 0, stream>>>(xb, wkb, BSD, DD, 256, 256,
      (float*)0, 0, (const float*)0, 0, kb, BSD, 0);
  bgemm<<<dim3(50, 4, 4), 256, 0, stream>>>(xb, wvb, BSD, DD, 256, 256,
      (float*)0, 0, (const float*)0, 0, vb, BSD, 0);
  attn_kernel<<<K_ * B_ * H_, 256, 0, stream>>>(qb, kb, vb, xb);  // o -> xb
  // O projection + residual -> hbuf fp32
  bgemm<<<dim3(50, 4, 4), 256, 0, stream>>>(xb, wob, BSD, DD, 256, 256,
      hbuf, BSD, hbuf, BSD, (unsigned short*)0, 0, 0);
  ln_bf16<<<3200, 256, 0, stream>>>(hbuf, xb, ln2g, ln2b);  // y -> xb
  // FFN1: gelu(y@W1) -> tb bf16
  bgemm<<<dim3(50, 16, 4), 256, 0, stream>>>(xb, w1b, BSD, DH4, 1024, 256,
      (float*)0, 0, (const float*)0, 0, tb, T4, 1);
  // FFN2: t@W2 + h -> hbuf fp32
  bgemm<<<dim3(50, 4, 4), 256, 0, stream>>>(tb, w2b, T4, DH4, 256, 1024,
      hbuf, BSD, hbuf, BSD, (unsigned short*)0, 0, 0);
  combine_kernel<<<800, 256, 0, stream>>>(gates, hbuf, out);
}

// Round 3
// 704.702 us; speedup vs baseline: 1.2535x; 1.2535x over previous
//
#include <hip/hip_runtime.h>
#include <hip/hip_bf16.h>
#include <math.h>

#define K_ 4
#define B_ 64
#define S_ 50
#define D_ 256
#define V_ 40000
#define H_ 4
#define DH_ 64
#define NEG_ (-1e9f)
#define SCALE_ 0.125f

typedef __attribute__((ext_vector_type(8))) __bf16 bf16x8v;
typedef __attribute__((ext_vector_type(4))) float f32x4v;

// ---------- helpers ----------
__device__ __forceinline__ float wred_sum(float v) {
#pragma unroll
  for (int off = 32; off > 0; off >>= 1) v += __shfl_xor(v, off, 64);
  return v;
}
__device__ __forceinline__ float wred_max(float v) {
#pragma unroll
  for (int off = 32; off > 0; off >>= 1) v = fmaxf(v, __shfl_xor(v, off, 64));
  return v;
}
__device__ __forceinline__ float softplusf(float x) {
  return (x > 20.f) ? x : log1pf(expf(x));
}
__device__ __forceinline__ float geluf(float x) {
  const float c = 0.7978845608028654f;  // sqrt(2/pi)
  float x3 = x * x * x;
  return 0.5f * x * (1.f + tanhf(c * (x + 0.044715f * x3)));
}
__device__ __forceinline__ float bf2f(unsigned int u) {
  return __uint_as_float(u << 16);
}
__device__ __forceinline__ unsigned short f2bf(float f) {
  unsigned u = __float_as_uint(f);
  return (unsigned short)((u + 0x7fffu + ((u >> 16) & 1u)) >> 16);
}
__device__ __forceinline__ void unp8(uint4 a, float* d) {
  d[0] = bf2f(a.x & 0xffffu); d[1] = bf2f(a.x >> 16);
  d[2] = bf2f(a.y & 0xffffu); d[3] = bf2f(a.y >> 16);
  d[4] = bf2f(a.z & 0xffffu); d[5] = bf2f(a.z >> 16);
  d[6] = bf2f(a.w & 0xffffu); d[7] = bf2f(a.w >> 16);
}

// ---------- weight cast fp32 -> bf16, QKV packed [K][D][768] ----------
// layout: wqkv(2359296) wo(262144) w1(1048576) w2(1048576)
__global__ __launch_bounds__(256) void cast_weights(
    const float* __restrict__ wq, const float* __restrict__ wk,
    const float* __restrict__ wv, const float* __restrict__ wo,
    const float* __restrict__ w1, const float* __restrict__ w2,
    unsigned short* __restrict__ wqkv, unsigned short* __restrict__ wob,
    unsigned short* __restrict__ w1b, unsigned short* __restrict__ w2b) {
  long i4 = ((long)blockIdx.x * 256 + threadIdx.x) * 4;
  const float* src;
  unsigned short* dst;
  if (i4 < 786432) {  // Wq/Wk/Wv -> packed
    int sect = (int)(i4 / 262144);          // 0=q 1=k 2=v
    long e = i4 - (long)sect * 262144;
    src = (sect == 0) ? wq : (sect == 1) ? wk : wv;
    int k = (int)(e >> 16);
    int rem = (int)(e & 65535);
    int d = rem >> 8, n = rem & 255;
    float4 v = *(const float4*)(src + e);
    ushort4 o;
    o.x = f2bf(v.x); o.y = f2bf(v.y); o.z = f2bf(v.z); o.w = f2bf(v.w);
    *(ushort4*)(wqkv + (long)k * 196608 + (long)d * 768 + sect * 256 + n) = o;
    return;
  }
  long e;
  if (i4 < 1048576) { src = wo; e = i4 - 786432; dst = wob; }
  else if (i4 < 2097152) { src = w1; e = i4 - 1048576; dst = w1b; }
  else { src = w2; e = i4 - 2097152; dst = w2b; }
  float4 v = *(const float4*)(src + e);
  ushort4 o;
  o.x = f2bf(v.x); o.y = f2bf(v.y); o.z = f2bf(v.z); o.w = f2bf(v.w);
  *(ushort4*)(dst + e) = o;
}

// ---------- gating ----------
__global__ __launch_bounds__(256) void gate_kernel(
    const int* __restrict__ ids, const float* __restrict__ emb,
    const float* __restrict__ Wg, const float* __restrict__ Wn,
    const float* __restrict__ eps, float* __restrict__ gates) {
  int w = threadIdx.x >> 6, lane = threadIdx.x & 63;
  int item = blockIdx.x * 4 + w;  // b*S+s
  int b = item / S_, s = item % S_;
  int d0 = lane * 4;
  float4 hs = make_float4(0.f, 0.f, 0.f, 0.f);
#pragma unroll
  for (int k = 0; k < K_; ++k) {
    int id = ids[(k * B_ + b) * S_ + s];
    const float4 e = *(const float4*)(emb + ((long)k * V_ + id) * D_ + d0);
    hs.x += e.x; hs.y += e.y; hs.z += e.z; hs.w += e.w;
  }
  hs.x *= 0.25f; hs.y *= 0.25f; hs.z *= 0.25f; hs.w *= 0.25f;
  float logit[4];
#pragma unroll
  for (int j = 0; j < K_; ++j) {
    float pg = hs.x * Wg[(d0 + 0) * K_ + j] + hs.y * Wg[(d0 + 1) * K_ + j] +
               hs.z * Wg[(d0 + 2) * K_ + j] + hs.w * Wg[(d0 + 3) * K_ + j];
    float pn = hs.x * Wn[(d0 + 0) * K_ + j] + hs.y * Wn[(d0 + 1) * K_ + j] +
               hs.z * Wn[(d0 + 2) * K_ + j] + hs.w * Wn[(d0 + 3) * K_ + j];
    pg = wred_sum(pg);
    pn = wred_sum(pn);
    logit[j] = pg + softplusf(pn) * eps[item * K_ + j];
  }
  if (lane == 0) {
    int i0 = 0; float v0 = logit[0];
    for (int j = 1; j < K_; ++j) if (logit[j] > v0) { v0 = logit[j]; i0 = j; }
    int i1 = -1; float v1 = 0.f;
    for (int j = 0; j < K_; ++j)
      if (j != i0 && (i1 < 0 || logit[j] > v1)) { v1 = logit[j]; i1 = j; }
    float w0 = 1.f / (1.f + expf(v1 - v0));
    float w1 = 1.f - w0;
#pragma unroll
    for (int j = 0; j < K_; ++j)
      gates[item * K_ + j] = (j == i0) ? w0 : ((j == i1) ? w1 : 0.f);
  }
}

// ---------- local aggregator: lane = neighbor j, 4 row-slices per (k,b) ----------
__global__ __launch_bounds__(256) void local_agg3(
    const int* __restrict__ items, const int* __restrict__ adj,
    const int* __restrict__ alias_, const float* __restrict__ emb,
    const float* __restrict__ agg_a, float* __restrict__ h_out) {
  __shared__ float hg[S_][257];   // +1 pad; all read patterns <=2-way (free)
  __shared__ float a_s[4][257];
  __shared__ int alias_s[S_];
  int blk = blockIdx.x;
  int q = blk & 3, kb = blk >> 2;
  int k = kb / B_, b = kb % B_;
  int t = threadIdx.x;
  // conflict-free staging: lane -> consecutive column
  for (int f = t; f < S_ * 256; f += 256) {
    int row = f >> 8, col = f & 255;
    int g = items[kb * S_ + row];  // wave-uniform scalar load
    hg[row][col] = emb[((long)k * V_ + g) * D_ + col];
  }
  for (int f = t; f < 4 * 256; f += 256) {
    int row = f >> 8, col = f & 255;
    a_s[row][col] = agg_a[((long)k * 4 + row) * D_ + col];
  }
  if (t < S_) alias_s[t] = alias_[b * S_ + t];
  __syncthreads();
  int w = t >> 6, lane = t & 63;
  int r0 = q * 13 - (q == 3 ? 1 : 0);  // 0,13,26,38
  int cnt = (q < 2) ? 13 : 12;
  for (int i = r0 + w; i < r0 + cnt; i += 4) {
    int r = 0;
    if (lane < S_) r = adj[((long)b * S_ + i) * S_ + lane];
    int jj = (lane < S_) ? lane : 0;
    int rr = (r > 0) ? (r - 1) : 0;
    const float* hi = hg[i];
    const float* ar = a_s[rr];
    const float* hj = hg[jj];
    float d0 = 0.f, d1 = 0.f, d2 = 0.f, d3 = 0.f;
#pragma unroll 8
    for (int d = 0; d < D_; d += 4) {
      d0 = fmaf(hi[d + 0] * ar[d + 0], hj[d + 0], d0);
      d1 = fmaf(hi[d + 1] * ar[d + 1], hj[d + 1], d1);
      d2 = fmaf(hi[d + 2] * ar[d + 2], hj[d + 2], d2);
      d3 = fmaf(hi[d + 3] * ar[d + 3], hj[d + 3], d3);
    }
    float dot = (d0 + d1) + (d2 + d3);
    float val;
    if (lane < S_) val = (r > 0) ? ((dot >= 0.f) ? dot : 0.2f * dot) : NEG_;
    else val = -INFINITY;  // pads -> exp 0 even in all-NEG rows
    float m = wred_max(val);
    float p = expf(val - m);
    float ssum = wred_sum(p);
    float alpha = p / ssum;
    float acc0 = 0, acc1 = 0, acc2 = 0, acc3 = 0;
    for (int j = 0; j < S_; ++j) {
      float aj = __shfl(alpha, j, 64);
      acc0 = fmaf(aj, hg[j][lane], acc0);
      acc1 = fmaf(aj, hg[j][lane + 64], acc1);
      acc2 = fmaf(aj, hg[j][lane + 128], acc2);
      acc3 = fmaf(aj, hg[j][lane + 192], acc3);
    }
    for (int s = 0; s < S_; ++s) {
      if (alias_s[s] == i) {  // wave-uniform
        float* dst = h_out + ((long)kb * S_ + s) * D_;
        dst[lane] = acc0; dst[lane + 64] = acc1;
        dst[lane + 128] = acc2; dst[lane + 192] = acc3;
      }
    }
  }
}

// ---------- layernorm -> bf16 out (one wave per row) ----------
__global__ __launch_bounds__(256) void ln_bf16(
    const float* __restrict__ x, unsigned short* __restrict__ y,
    const float* __restrict__ g, const float* __restrict__ bta) {
  int w = threadIdx.x >> 6, lane = threadIdx.x & 63;
  long row = (long)blockIdx.x * 4 + w;  // < K*B*S
  int k = (int)(row / (B_ * S_));
  const float4 v = *(const float4*)(x + row * D_ + lane * 4);
  float sum = wred_sum(v.x + v.y + v.z + v.w);
  float sq = wred_sum(v.x * v.x + v.y * v.y + v.z * v.z + v.w * v.w);
  float mean = sum * (1.f / D_);
  float var = sq * (1.f / D_) - mean * mean;
  float rs = rsqrtf(var + 1e-5f);
  const float4 gv = *(const float4*)(g + k * D_ + lane * 4);
  const float4 bv = *(const float4*)(bta + k * D_ + lane * 4);
  ushort4 o;
  o.x = f2bf((v.x - mean) * rs * gv.x + bv.x);
  o.y = f2bf((v.y - mean) * rs * gv.y + bv.y);
  o.z = f2bf((v.z - mean) * rs * gv.z + bv.z);
  o.w = f2bf((v.w - mean) * rs * gv.w + bv.w);
  *(ushort4*)(y + row * D_ + lane * 4) = o;
}

// ---------- bf16 MFMA GEMM: 64x64 tile, BK=32 ----------
__global__ __launch_bounds__(256) void bgemm(
    const unsigned short* __restrict__ A, const unsigned short* __restrict__ B,
    long strideA, long strideB, int N, int Kd,
    float* __restrict__ Cf, long strideCf,
    const float* __restrict__ R, long strideR,
    unsigned short* __restrict__ Cb, long strideCb, int act) {
  __shared__ unsigned short sA[64][40];
  __shared__ unsigned short sB[64][40];
  int z = blockIdx.z;
  A += (long)z * strideA;
  B += (long)z * strideB;
  int t = threadIdx.x, w = t >> 6, lane = t & 63;
  int row0 = blockIdx.x * 64, col0 = blockIdx.y * 64;
  f32x4v acc[4];
#pragma unroll
  for (int nt = 0; nt < 4; ++nt) acc[nt] = (f32x4v){0.f, 0.f, 0.f, 0.f};
  int ar = t >> 2, ac = (t & 3) * 8;
  int bk = t >> 3, bn = (t & 7) * 8;
  int m16 = lane & 15, kg = (lane >> 4) * 8;
  for (int k0 = 0; k0 < Kd; k0 += 32) {
    uint4 av = *(const uint4*)(A + (long)(row0 + ar) * Kd + k0 + ac);
    uint4 bv = *(const uint4*)(B + (long)(k0 + bk) * N + col0 + bn);
    __syncthreads();
    *(uint4*)&sA[ar][ac] = av;
    sB[bn + 0][bk] = (unsigned short)(bv.x & 0xffffu);
    sB[bn + 1][bk] = (unsigned short)(bv.x >> 16);
    sB[bn + 2][bk] = (unsigned short)(bv.y & 0xffffu);
    sB[bn + 3][bk] = (unsigned short)(bv.y >> 16);
    sB[bn + 4][bk] = (unsigned short)(bv.z & 0xffffu);
    sB[bn + 5][bk] = (unsigned short)(bv.z >> 16);
    sB[bn + 6][bk] = (unsigned short)(bv.w & 0xffffu);
    sB[bn + 7][bk] = (unsigned short)(bv.w >> 16);
    __syncthreads();
    bf16x8v af = *(const bf16x8v*)&sA[w * 16 + m16][kg];
#pragma unroll
    for (int nt = 0; nt < 4; ++nt) {
      bf16x8v bf = *(const bf16x8v*)&sB[nt * 16 + m16][kg];
      acc[nt] = __builtin_amdgcn_mfma_f32_16x16x32_bf16(af, bf, acc[nt], 0, 0, 0);
    }
  }
  int rbase = row0 + w * 16 + (lane >> 4) * 4;
  int cb = lane & 15;
#pragma unroll
  for (int nt = 0; nt < 4; ++nt) {
#pragma unroll
    for (int i2 = 0; i2 < 4; ++i2) {
      long off = (long)(rbase + i2) * N + col0 + nt * 16 + cb;
      float vv = acc[nt][i2];
      if (R) vv += R[(long)z * strideR + off];
      if (act == 1) vv = geluf(vv);
      if (Cf) Cf[(long)z * strideCf + off] = vv;
      if (Cb) Cb[(long)z * strideCb + off] = f2bf(vv);
    }
  }
}

// ---------- causal MHA: block per (k,b,head); packed qkv [K*B*S][768] ----------
__global__ __launch_bounds__(256) void attn_kernel(
    const unsigned short* __restrict__ qkv, unsigned short* __restrict__ o) {
  __shared__ float qs[S_][65], ks[S_][65], vs[S_][65];
  int idx = blockIdx.x;
  int h = idx & 3;       // H_=4
  int kb = idx >> 2;     // k*B+b
  long base = (long)kb * S_ * 768;
  int t = threadIdx.x;
  for (int f = t; f < S_ * 8; f += 256) {
    int row = f >> 3, c8 = (f & 7) * 8;
    long g = base + (long)row * 768 + h * DH_ + c8;
    unp8(*(const uint4*)(qkv + g), &qs[row][c8]);
    unp8(*(const uint4*)(qkv + g + 256), &ks[row][c8]);
    unp8(*(const uint4*)(qkv + g + 512), &vs[row][c8]);
  }
  __syncthreads();
  int w = t >> 6, lane = t & 63;
  for (int i = w; i < S_; i += 4) {
    int jj = (lane < S_) ? lane : 0;
    float dot = 0.f;
#pragma unroll
    for (int d = 0; d < DH_; ++d) dot = fmaf(qs[i][d], ks[jj][d], dot);
    float val = (lane <= i) ? dot * SCALE_ : ((lane < S_) ? NEG_ : -INFINITY);
    float m = wred_max(val);
    float p = expf(val - m);
    float ssum = wred_sum(p);
    float pr = p / ssum;
    float acc = 0.f;
    for (int j = 0; j <= i; ++j)
      acc = fmaf(__shfl(pr, j, 64), vs[j][lane], acc);
    o[((long)kb * S_ + i) * D_ + h * DH_ + lane] = f2bf(acc);
  }
}

// ---------- gated combine ----------
__global__ __launch_bounds__(256) void combine_kernel(
    const float* __restrict__ gates, const float* __restrict__ h,
    float* __restrict__ out) {
  int w = threadIdx.x >> 6, lane = threadIdx.x & 63;
  int item = blockIdx.x * 4 + w;
  float g0 = gates[item * 4 + 0], g1 = gates[item * 4 + 1];
  float g2 = gates[item * 4 + 2], g3 = gates[item * 4 + 3];
  long off = (long)item * D_ + lane * 4;
  const long PK = (long)B_ * S_ * D_;
  float4 a = *(const float4*)(h + off);
  float4 b = *(const float4*)(h + PK + off);
  float4 c = *(const float4*)(h + 2 * PK + off);
  float4 d = *(const float4*)(h + 3 * PK + off);
  float4 o;
  o.x = g0 * a.x + g1 * b.x + g2 * c.x + g3 * d.x;
  o.y = g0 * a.y + g1 * b.y + g2 * c.y + g3 * d.y;
  o.z = g0 * a.z + g1 * b.z + g2 * c.z + g3 * d.z;
  o.w = g0 * a.w + g1 * b.w + g2 * c.w + g3 * d.w;
  *(float4*)(out + off) = o;
}

extern "C" void kernel_launch(void* const* d_in, const int* in_sizes, int n_in,
                              void* d_out, int out_size, void* d_ws,
                              size_t ws_size, hipStream_t stream) {
  const int* ids = (const int*)d_in[0];
  const int* items = (const int*)d_in[1];
  const int* adj = (const int*)d_in[2];
  const int* alias = (const int*)d_in[3];
  const float* eps = (const float*)d_in[4];
  const float* emb = (const float*)d_in[5];
  const float* agg_a = (const float*)d_in[6];
  const float* Wq = (const float*)d_in[7];
  const float* Wk = (const float*)d_in[8];
  const float* Wv = (const float*)d_in[9];
  const float* Wo = (const float*)d_in[10];
  const float* ln1g = (const float*)d_in[11];
  const float* ln1b = (const float*)d_in[12];
  const float* W1 = (const float*)d_in[13];
  const float* W2 = (const float*)d_in[14];
  const float* ln2g = (const float*)d_in[15];
  const float* ln2b = (const float*)d_in[16];
  const float* Wg = (const float*)d_in[17];
  const float* Wn = (const float*)d_in[18];
  float* out = (float*)d_out;

  const long BSD = (long)B_ * S_ * D_;  // 819200
  float* ws = (float*)d_ws;
  float* gates = ws;                    // 16384 fp32
  float* hbuf = ws + 16384;             // [K,B,S,D] fp32 residual stream
  unsigned short* ub = (unsigned short*)(ws + 16384 + 4 * BSD);
  unsigned short* xb = ub;              // x / attn-o / y slot [K,B,S,D] bf16
  unsigned short* qkvb = ub + 3276800;  // [K,B*S,768] = 9830400
  unsigned short* tb = qkvb;            // FFN hidden [K,B*S,1024] = 13107200
  unsigned short* wqkvb = ub + 16384000;   // 2359296
  unsigned short* wob = wqkvb + 2359296;   // 262144
  unsigned short* w1b = wob + 262144;      // 1048576
  unsigned short* w2b = w1b + 1048576;     // 1048576

  const long DD = 65536, DH4 = 262144, T4 = 3276800;

  cast_weights<<<3072, 256, 0, stream>>>(Wq, Wk, Wv, Wo, W1, W2,
                                         wqkvb, wob, w1b, w2b);
  gate_kernel<<<800, 256, 0, stream>>>(ids, emb, Wg, Wn, eps, gates);
  local_agg3<<<1024, 256, 0, stream>>>(items, adj, alias, emb, agg_a, hbuf);
  ln_bf16<<<3200, 256, 0, stream>>>(hbuf, xb, ln1g, ln1b);
  // fused QKV projection -> qkvb
  bgemm<<<dim3(50, 12, 4), 256, 0, stream>>>(xb, wqkvb, BSD, 196608, 768, 256,
      (float*)0, 0, (const float*)0, 0, qkvb, 2457600, 0);
  attn_kernel<<<K_ * B_ * H_, 256, 0, stream>>>(qkvb, xb);  // o -> xb
  // O projection + residual -> hbuf fp32
  bgemm<<<dim3(50, 4, 4), 256, 0, stream>>>(xb, wob, BSD, DD, 256, 256,
      hbuf, BSD, hbuf, BSD, (unsigned short*)0, 0, 0);
  ln_bf16<<<3200, 256, 0, stream>>>(hbuf, xb, ln2g, ln2b);  // y -> xb
  // FFN1: gelu(y@W1) -> tb bf16
  bgemm<<<dim3(50, 16, 4), 256, 0, stream>>>(xb, w1b, BSD, DH4, 1024, 256,
      (float*)0, 0, (const float*)0, 0, tb, T4, 1);
  // FFN2: t@W2 + h -> hbuf fp32
  bgemm<<<dim3(50, 4, 4), 256, 0, stream>>>(tb, w2b, T4, DH4, 256, 1024,
      hbuf, BSD, hbuf, BSD, (unsigned short*)0, 0, 0);
  combine_kernel<<<800, 256, 0, stream>>>(gates, hbuf, out);
}

// Round 4
// 492.282 us; speedup vs baseline: 1.7943x; 1.4315x over previous
//
#include <hip/hip_runtime.h>
#include <hip/hip_bf16.h>
#include <math.h>

#define K_ 4
#define B_ 64
#define S_ 50
#define D_ 256
#define V_ 40000
#define H_ 4
#define DH_ 64
#define NEG_ (-1e9f)
#define SCALE_ 0.125f

typedef __attribute__((ext_vector_type(8))) __bf16 bf16x8v;
typedef __attribute__((ext_vector_type(4))) float f32x4v;

// ---------- helpers ----------
__device__ __forceinline__ float wred_sum(float v) {
#pragma unroll
  for (int off = 32; off > 0; off >>= 1) v += __shfl_xor(v, off, 64);
  return v;
}
__device__ __forceinline__ float wred_max(float v) {
#pragma unroll
  for (int off = 32; off > 0; off >>= 1) v = fmaxf(v, __shfl_xor(v, off, 64));
  return v;
}
__device__ __forceinline__ float softplusf(float x) {
  return (x > 20.f) ? x : log1pf(expf(x));
}
__device__ __forceinline__ float geluf(float x) {
  const float c = 0.7978845608028654f;  // sqrt(2/pi)
  float x3 = x * x * x;
  return 0.5f * x * (1.f + tanhf(c * (x + 0.044715f * x3)));
}
__device__ __forceinline__ float bf2f(unsigned int u) {
  return __uint_as_float(u << 16);
}
__device__ __forceinline__ unsigned short f2bf(float f) {
  unsigned u = __float_as_uint(f);
  return (unsigned short)((u + 0x7fffu + ((u >> 16) & 1u)) >> 16);
}
__device__ __forceinline__ void unp8(uint4 a, float* d) {
  d[0] = bf2f(a.x & 0xffffu); d[1] = bf2f(a.x >> 16);
  d[2] = bf2f(a.y & 0xffffu); d[3] = bf2f(a.y >> 16);
  d[4] = bf2f(a.z & 0xffffu); d[5] = bf2f(a.z >> 16);
  d[6] = bf2f(a.w & 0xffffu); d[7] = bf2f(a.w >> 16);
}
__device__ __forceinline__ bf16x8v cvt8(float4 a, float4 b) {
  bf16x8v r;
  r[0] = (__bf16)a.x; r[1] = (__bf16)a.y; r[2] = (__bf16)a.z; r[3] = (__bf16)a.w;
  r[4] = (__bf16)b.x; r[5] = (__bf16)b.y; r[6] = (__bf16)b.z; r[7] = (__bf16)b.w;
  return r;
}

// ---------- weight cast fp32 -> bf16, QKV packed [K][D][768] ----------
__global__ __launch_bounds__(256) void cast_weights(
    const float* __restrict__ wq, const float* __restrict__ wk,
    const float* __restrict__ wv, const float* __restrict__ wo,
    const float* __restrict__ w1, const float* __restrict__ w2,
    unsigned short* __restrict__ wqkv, unsigned short* __restrict__ wob,
    unsigned short* __restrict__ w1b, unsigned short* __restrict__ w2b) {
  long i4 = ((long)blockIdx.x * 256 + threadIdx.x) * 4;
  const float* src;
  unsigned short* dst;
  if (i4 < 786432) {  // Wq/Wk/Wv -> packed
    int sect = (int)(i4 / 262144);  // 0=q 1=k 2=v
    long e = i4 - (long)sect * 262144;
    src = (sect == 0) ? wq : (sect == 1) ? wk : wv;
    int k = (int)(e >> 16);
    int rem = (int)(e & 65535);
    int d = rem >> 8, n = rem & 255;
    float4 v = *(const float4*)(src + e);
    ushort4 o;
    o.x = f2bf(v.x); o.y = f2bf(v.y); o.z = f2bf(v.z); o.w = f2bf(v.w);
    *(ushort4*)(wqkv + (long)k * 196608 + (long)d * 768 + sect * 256 + n) = o;
    return;
  }
  long e;
  if (i4 < 1048576) { src = wo; e = i4 - 786432; dst = wob; }
  else if (i4 < 2097152) { src = w1; e = i4 - 1048576; dst = w1b; }
  else { src = w2; e = i4 - 2097152; dst = w2b; }
  float4 v = *(const float4*)(src + e);
  ushort4 o;
  o.x = f2bf(v.x); o.y = f2bf(v.y); o.z = f2bf(v.z); o.w = f2bf(v.w);
  *(ushort4*)(dst + e) = o;
}

// ---------- gating ----------
__global__ __launch_bounds__(256) void gate_kernel(
    const int* __restrict__ ids, const float* __restrict__ emb,
    const float* __restrict__ Wg, const float* __restrict__ Wn,
    const float* __restrict__ eps, float* __restrict__ gates) {
  int w = threadIdx.x >> 6, lane = threadIdx.x & 63;
  int item = blockIdx.x * 4 + w;  // b*S+s
  int b = item / S_, s = item % S_;
  int d0 = lane * 4;
  float4 hs = make_float4(0.f, 0.f, 0.f, 0.f);
#pragma unroll
  for (int k = 0; k < K_; ++k) {
    int id = ids[(k * B_ + b) * S_ + s];
    const float4 e = *(const float4*)(emb + ((long)k * V_ + id) * D_ + d0);
    hs.x += e.x; hs.y += e.y; hs.z += e.z; hs.w += e.w;
  }
  hs.x *= 0.25f; hs.y *= 0.25f; hs.z *= 0.25f; hs.w *= 0.25f;
  float logit[4];
#pragma unroll
  for (int j = 0; j < K_; ++j) {
    float pg = hs.x * Wg[(d0 + 0) * K_ + j] + hs.y * Wg[(d0 + 1) * K_ + j] +
               hs.z * Wg[(d0 + 2) * K_ + j] + hs.w * Wg[(d0 + 3) * K_ + j];
    float pn = hs.x * Wn[(d0 + 0) * K_ + j] + hs.y * Wn[(d0 + 1) * K_ + j] +
               hs.z * Wn[(d0 + 2) * K_ + j] + hs.w * Wn[(d0 + 3) * K_ + j];
    pg = wred_sum(pg);
    pn = wred_sum(pn);
    logit[j] = pg + softplusf(pn) * eps[item * K_ + j];
  }
  if (lane == 0) {
    int i0 = 0; float v0 = logit[0];
    for (int j = 1; j < K_; ++j) if (logit[j] > v0) { v0 = logit[j]; i0 = j; }
    int i1 = -1; float v1 = 0.f;
    for (int j = 0; j < K_; ++j)
      if (j != i0 && (i1 < 0 || logit[j] > v1)) { v1 = logit[j]; i1 = j; }
    float w0 = 1.f / (1.f + expf(v1 - v0));
    float w1 = 1.f - w0;
#pragma unroll
    for (int j = 0; j < K_; ++j)
      gates[item * K_ + j] = (j == i0) ? w0 : ((j == i1) ? w1 : 0.f);
  }
}

// ---------- local aggregator via MFMA ----------
// one block per (k,b). e_r = (hg .* a_r) @ hg^T via mfma (padded 64x64),
// masked-select by adj, row softmax, h_local = alpha @ hg via mfma.
// writes h_raw [K*B, S, D] fp32 (pre-alias order).
__global__ __launch_bounds__(256) void local_agg4(
    const int* __restrict__ items, const int* __restrict__ adj,
    const float* __restrict__ emb, const float* __restrict__ agg_a,
    float* __restrict__ h_raw) {
  __shared__ __bf16 hgb[64][264];        // 33792 B ; row stride 528B (16B mult)
  __shared__ float e_f[50][68];          // 13600 B
  __shared__ __bf16 alp[64][72];         //  9216 B ; row stride 144B (16B mult)
  __shared__ unsigned char adj_s[64][64];  // 4096 B
  __shared__ __bf16 a_sb[4][264];        //  2112 B   (total ~62.8 KB)
  int kb = blockIdx.x;
  int k = kb >> 6, b = kb & 63;  // B_=64
  int t = threadIdx.x;
  // stage hg (bf16, zero-padded rows 50..63): 64 rows x 32 chunks of 8
  for (int c = t; c < 2048; c += 256) {
    int row = c >> 5, c8 = (c & 31) * 8;
    bf16x8v val;
    if (row < S_) {
      int g = items[kb * S_ + row];
      const float* src = emb + ((long)k * V_ + g) * D_ + c8;
      val = cvt8(*(const float4*)src, *(const float4*)(src + 4));
    } else {
#pragma unroll
      for (int e = 0; e < 8; ++e) val[e] = (__bf16)0.f;
    }
    *(bf16x8v*)&hgb[row][c8] = val;
  }
  if (t < 128) {
    int row = t >> 5, c8 = (t & 31) * 8;
    const float* src = agg_a + ((long)k * 4 + row) * D_ + c8;
    *(bf16x8v*)&a_sb[row][c8] = cvt8(*(const float4*)src, *(const float4*)(src + 4));
  }
  for (int c = t; c < 4096; c += 256) {
    int i = c >> 6, j = c & 63;
    adj_s[i][j] = (i < S_ && j < S_)
                      ? (unsigned char)adj[((long)b * S_ + i) * S_ + j] : 0;
  }
  __syncthreads();
  int w = t >> 6, lane = t & 63;
  int m16 = lane & 15, quad = lane >> 4;
  // ---- e phase: wave w owns m-tile w (rows w*16..w*16+15) ----
  float e_sel[4][4];
#pragma unroll
  for (int nt = 0; nt < 4; ++nt)
#pragma unroll
    for (int rg = 0; rg < 4; ++rg) e_sel[nt][rg] = NEG_;
#pragma unroll
  for (int r = 0; r < 4; ++r) {
    f32x4v acc[4];
#pragma unroll
    for (int nt = 0; nt < 4; ++nt) acc[nt] = (f32x4v){0.f, 0.f, 0.f, 0.f};
#pragma unroll
    for (int k0 = 0; k0 < 8; ++k0) {
      int kc = k0 * 32 + quad * 8;
      bf16x8v hr = *(const bf16x8v*)&hgb[w * 16 + m16][kc];
      bf16x8v ar = *(const bf16x8v*)&a_sb[r][kc];
      bf16x8v af;
#pragma unroll
      for (int e = 0; e < 8; ++e) af[e] = (__bf16)((float)hr[e] * (float)ar[e]);
#pragma unroll
      for (int nt = 0; nt < 4; ++nt) {
        bf16x8v bf = *(const bf16x8v*)&hgb[nt * 16 + m16][kc];
        acc[nt] = __builtin_amdgcn_mfma_f32_16x16x32_bf16(af, bf, acc[nt], 0, 0, 0);
      }
    }
#pragma unroll
    for (int nt = 0; nt < 4; ++nt)
#pragma unroll
      for (int rg = 0; rg < 4; ++rg) {
        int i = w * 16 + quad * 4 + rg, j = nt * 16 + m16;
        if (adj_s[i][j] == r + 1) {
          float v = acc[nt][rg];
          e_sel[nt][rg] = (v >= 0.f) ? v : 0.2f * v;
        }
      }
  }
#pragma unroll
  for (int nt = 0; nt < 4; ++nt)
#pragma unroll
    for (int rg = 0; rg < 4; ++rg) {
      int i = w * 16 + quad * 4 + rg;
      if (i < S_) e_f[i][nt * 16 + m16] = e_sel[nt][rg];
    }
  __syncthreads();
  // ---- softmax rows (lane = j) ----
  for (int i = w; i < S_; i += 4) {
    float val = (lane < S_) ? e_f[i][lane] : -INFINITY;
    float m = wred_max(val);
    float p = expf(val - m);
    float ssum = wred_sum(p);
    alp[i][lane] = (__bf16)(p / ssum);
  }
  __syncthreads();
  // ---- h_local = alpha @ hg : wave w owns m-tile w ----
#pragma unroll 4
  for (int nt = 0; nt < 16; ++nt) {
    f32x4v acc = (f32x4v){0.f, 0.f, 0.f, 0.f};
#pragma unroll
    for (int k0 = 0; k0 < 2; ++k0) {
      int jb = k0 * 32 + quad * 8;
      bf16x8v af = *(const bf16x8v*)&alp[w * 16 + m16][jb];
      bf16x8v bf;
#pragma unroll
      for (int tt = 0; tt < 8; ++tt) bf[tt] = hgb[jb + tt][nt * 16 + m16];
      acc = __builtin_amdgcn_mfma_f32_16x16x32_bf16(af, bf, acc, 0, 0, 0);
    }
#pragma unroll
    for (int rg = 0; rg < 4; ++rg) {
      int i = w * 16 + quad * 4 + rg;
      if (i < S_)
        h_raw[((long)kb * S_ + i) * D_ + nt * 16 + m16] = acc[rg];
    }
  }
}

// ---------- alias gather + LN1: h[s]=h_raw[alias[s]] -> hbuf f32 + xb bf16 ----------
__global__ __launch_bounds__(256) void gather_ln(
    const float* __restrict__ h_raw, const int* __restrict__ alias_,
    float* __restrict__ hbuf, unsigned short* __restrict__ xb,
    const float* __restrict__ g, const float* __restrict__ bta) {
  int kb = blockIdx.x;
  int k = kb >> 6, b = kb & 63;
  int w = threadIdx.x >> 6, lane = threadIdx.x & 63;
  for (int s = w; s < S_; s += 4) {
    int src = alias_[b * S_ + s];
    const float4 v = *(const float4*)(h_raw + ((long)kb * S_ + src) * D_ + lane * 4);
    long off = ((long)kb * S_ + s) * D_ + lane * 4;
    *(float4*)(hbuf + off) = v;
    float sum = wred_sum(v.x + v.y + v.z + v.w);
    float sq = wred_sum(v.x * v.x + v.y * v.y + v.z * v.z + v.w * v.w);
    float mean = sum * (1.f / D_);
    float var = sq * (1.f / D_) - mean * mean;
    float rs = rsqrtf(var + 1e-5f);
    const float4 gv = *(const float4*)(g + k * D_ + lane * 4);
    const float4 bv = *(const float4*)(bta + k * D_ + lane * 4);
    ushort4 o;
    o.x = f2bf((v.x - mean) * rs * gv.x + bv.x);
    o.y = f2bf((v.y - mean) * rs * gv.y + bv.y);
    o.z = f2bf((v.z - mean) * rs * gv.z + bv.z);
    o.w = f2bf((v.w - mean) * rs * gv.w + bv.w);
    *(ushort4*)(xb + off) = o;
  }
}

// ---------- layernorm -> bf16 out (one wave per row) ----------
__global__ __launch_bounds__(256) void ln_bf16(
    const float* __restrict__ x, unsigned short* __restrict__ y,
    const float* __restrict__ g, const float* __restrict__ bta) {
  int w = threadIdx.x >> 6, lane = threadIdx.x & 63;
  long row = (long)blockIdx.x * 4 + w;  // < K*B*S
  int k = (int)(row / (B_ * S_));
  const float4 v = *(const float4*)(x + row * D_ + lane * 4);
  float sum = wred_sum(v.x + v.y + v.z + v.w);
  float sq = wred_sum(v.x * v.x + v.y * v.y + v.z * v.z + v.w * v.w);
  float mean = sum * (1.f / D_);
  float var = sq * (1.f / D_) - mean * mean;
  float rs = rsqrtf(var + 1e-5f);
  const float4 gv = *(const float4*)(g + k * D_ + lane * 4);
  const float4 bv = *(const float4*)(bta + k * D_ + lane * 4);
  ushort4 o;
  o.x = f2bf((v.x - mean) * rs * gv.x + bv.x);
  o.y = f2bf((v.y - mean) * rs * gv.y + bv.y);
  o.z = f2bf((v.z - mean) * rs * gv.z + bv.z);
  o.w = f2bf((v.w - mean) * rs * gv.w + bv.w);
  *(ushort4*)(y + row * D_ + lane * 4) = o;
}

// ---------- bf16 MFMA GEMM: 64x64 tile, BK=32 ----------
__global__ __launch_bounds__(256) void bgemm(
    const unsigned short* __restrict__ A, const unsigned short* __restrict__ B,
    long strideA, long strideB, int N, int Kd,
    float* __restrict__ Cf, long strideCf,
    const float* __restrict__ R, long strideR,
    unsigned short* __restrict__ Cb, long strideCb, int act) {
  __shared__ unsigned short sA[64][40];
  __shared__ unsigned short sB[64][40];
  int z = blockIdx.z;
  A += (long)z * strideA;
  B += (long)z * strideB;
  int t = threadIdx.x, w = t >> 6, lane = t & 63;
  int row0 = blockIdx.x * 64, col0 = blockIdx.y * 64;
  f32x4v acc[4];
#pragma unroll
  for (int nt = 0; nt < 4; ++nt) acc[nt] = (f32x4v){0.f, 0.f, 0.f, 0.f};
  int ar = t >> 2, ac = (t & 3) * 8;
  int bk = t >> 3, bn = (t & 7) * 8;
  int m16 = lane & 15, kg = (lane >> 4) * 8;
  for (int k0 = 0; k0 < Kd; k0 += 32) {
    uint4 av = *(const uint4*)(A + (long)(row0 + ar) * Kd + k0 + ac);
    uint4 bv = *(const uint4*)(B + (long)(k0 + bk) * N + col0 + bn);
    __syncthreads();
    *(uint4*)&sA[ar][ac] = av;
    sB[bn + 0][bk] = (unsigned short)(bv.x & 0xffffu);
    sB[bn + 1][bk] = (unsigned short)(bv.x >> 16);
    sB[bn + 2][bk] = (unsigned short)(bv.y & 0xffffu);
    sB[bn + 3][bk] = (unsigned short)(bv.y >> 16);
    sB[bn + 4][bk] = (unsigned short)(bv.z & 0xffffu);
    sB[bn + 5][bk] = (unsigned short)(bv.z >> 16);
    sB[bn + 6][bk] = (unsigned short)(bv.w & 0xffffu);
    sB[bn + 7][bk] = (unsigned short)(bv.w >> 16);
    __syncthreads();
    bf16x8v af = *(const bf16x8v*)&sA[w * 16 + m16][kg];
#pragma unroll
    for (int nt = 0; nt < 4; ++nt) {
      bf16x8v bf = *(const bf16x8v*)&sB[nt * 16 + m16][kg];
      acc[nt] = __builtin_amdgcn_mfma_f32_16x16x32_bf16(af, bf, acc[nt], 0, 0, 0);
    }
  }
  int rbase = row0 + w * 16 + (lane >> 4) * 4;
  int cb = lane & 15;
#pragma unroll
  for (int nt = 0; nt < 4; ++nt) {
#pragma unroll
    for (int i2 = 0; i2 < 4; ++i2) {
      long off = (long)(rbase + i2) * N + col0 + nt * 16 + cb;
      float vv = acc[nt][i2];
      if (R) vv += R[(long)z * strideR + off];
      if (act == 1) vv = geluf(vv);
      if (Cf) Cf[(long)z * strideCf + off] = vv;
      if (Cb) Cb[(long)z * strideCb + off] = f2bf(vv);
    }
  }
}

// ---------- causal MHA: block per (k,b,head); packed qkv [K*B*S][768] ----------
__global__ __launch_bounds__(256) void attn_kernel(
    const unsigned short* __restrict__ qkv, unsigned short* __restrict__ o) {
  __shared__ float qs[S_][65], ks[S_][65], vs[S_][65];
  int idx = blockIdx.x;
  int h = idx & 3;       // H_=4
  int kb = idx >> 2;     // k*B+b
  long base = (long)kb * S_ * 768;
  int t = threadIdx.x;
  for (int f = t; f < S_ * 8; f += 256) {
    int row = f >> 3, c8 = (f & 7) * 8;
    long g = base + (long)row * 768 + h * DH_ + c8;
    unp8(*(const uint4*)(qkv + g), &qs[row][c8]);
    unp8(*(const uint4*)(qkv + g + 256), &ks[row][c8]);
    unp8(*(const uint4*)(qkv + g + 512), &vs[row][c8]);
  }
  __syncthreads();
  int w = t >> 6, lane = t & 63;
  for (int i = w; i < S_; i += 4) {
    int jj = (lane < S_) ? lane : 0;
    float dot = 0.f;
#pragma unroll
    for (int d = 0; d < DH_; ++d) dot = fmaf(qs[i][d], ks[jj][d], dot);
    float val = (lane <= i) ? dot * SCALE_ : ((lane < S_) ? NEG_ : -INFINITY);
    float m = wred_max(val);
    float p = expf(val - m);
    float ssum = wred_sum(p);
    float pr = p / ssum;
    float acc = 0.f;
    for (int j = 0; j <= i; ++j)
      acc = fmaf(__shfl(pr, j, 64), vs[j][lane], acc);
    o[((long)kb * S_ + i) * D_ + h * DH_ + lane] = f2bf(acc);
  }
}

// ---------- gated combine ----------
__global__ __launch_bounds__(256) void combine_kernel(
    const float* __restrict__ gates, const float* __restrict__ h,
    float* __restrict__ out) {
  int w = threadIdx.x >> 6, lane = threadIdx.x & 63;
  int item = blockIdx.x * 4 + w;
  float g0 = gates[item * 4 + 0], g1 = gates[item * 4 + 1];
  float g2 = gates[item * 4 + 2], g3 = gates[item * 4 + 3];
  long off = (long)item * D_ + lane * 4;
  const long PK = (long)B_ * S_ * D_;
  float4 a = *(const float4*)(h + off);
  float4 b = *(const float4*)(h + PK + off);
  float4 c = *(const float4*)(h + 2 * PK + off);
  float4 d = *(const float4*)(h + 3 * PK + off);
  float4 o;
  o.x = g0 * a.x + g1 * b.x + g2 * c.x + g3 * d.x;
  o.y = g0 * a.y + g1 * b.y + g2 * c.y + g3 * d.y;
  o.z = g0 * a.z + g1 * b.z + g2 * c.z + g3 * d.z;
  o.w = g0 * a.w + g1 * b.w + g2 * c.w + g3 * d.w;
  *(float4*)(out + off) = o;
}

extern "C" void kernel_launch(void* const* d_in, const int* in_sizes, int n_in,
                              void* d_out, int out_size, void* d_ws,
                              size_t ws_size, hipStream_t stream) {
  const int* ids = (const int*)d_in[0];
  const int* items = (const int*)d_in[1];
  const int* adj = (const int*)d_in[2];
  const int* alias = (const int*)d_in[3];
  const float* eps = (const float*)d_in[4];
  const float* emb = (const float*)d_in[5];
  const float* agg_a = (const float*)d_in[6];
  const float* Wq = (const float*)d_in[7];
  const float* Wk = (const float*)d_in[8];
  const float* Wv = (const float*)d_in[9];
  const float* Wo = (const float*)d_in[10];
  const float* ln1g = (const float*)d_in[11];
  const float* ln1b = (const float*)d_in[12];
  const float* W1 = (const float*)d_in[13];
  const float* W2 = (const float*)d_in[14];
  const float* ln2g = (const float*)d_in[15];
  const float* ln2b = (const float*)d_in[16];
  const float* Wg = (const float*)d_in[17];
  const float* Wn = (const float*)d_in[18];
  float* out = (float*)d_out;

  const long BSD = (long)B_ * S_ * D_;  // 819200
  float* ws = (float*)d_ws;
  float* gates = ws;                    // 16384 fp32
  float* hbuf = ws + 16384;             // [K,B,S,D] fp32 residual stream
  unsigned short* ub = (unsigned short*)(ws + 16384 + 4 * BSD);
  unsigned short* xb = ub;              // x / attn-o / y slot [K,B,S,D] bf16
  unsigned short* qkvb = ub + 3276800;  // [K,B*S,768] = 9830400
  unsigned short* tb = qkvb;            // FFN hidden [K,B*S,1024] = 13107200
  float* h_raw = (float*)qkvb;          // pre-alias h_local [K*B,S,D] (dead before QKV)
  unsigned short* wqkvb = ub + 16384000;   // 2359296
  unsigned short* wob = wqkvb + 2359296;   // 262144
  unsigned short* w1b = wob + 262144;      // 1048576
  unsigned short* w2b = w1b + 1048576;     // 1048576

  const long DD = 65536, DH4 = 262144, T4 = 3276800;

  cast_weights<<<3072, 256, 0, stream>>>(Wq, Wk, Wv, Wo, W1, W2,
                                         wqkvb, wob, w1b, w2b);
  gate_kernel<<<800, 256, 0, stream>>>(ids, emb, Wg, Wn, eps, gates);
  local_agg4<<<256, 256, 0, stream>>>(items, adj, emb, agg_a, h_raw);
  gather_ln<<<256, 256, 0, stream>>>(h_raw, alias, hbuf, xb, ln1g, ln1b);
  // fused QKV projection -> qkvb (h_raw dead from here)
  bgemm<<<dim3(50, 12, 4), 256, 0, stream>>>(xb, wqkvb, BSD, 196608, 768, 256,
      (float*)0, 0, (const float*)0, 0, qkvb, 2457600, 0);
  attn_kernel<<<K_ * B_ * H_, 256, 0, stream>>>(qkvb, xb);  // o -> xb
  // O projection + residual -> hbuf fp32
  bgemm<<<dim3(50, 4, 4), 256, 0, stream>>>(xb, wob, BSD, DD, 256, 256,
      hbuf, BSD, hbuf, BSD, (unsigned short*)0, 0, 0);
  ln_bf16<<<3200, 256, 0, stream>>>(hbuf, xb, ln2g, ln2b);  // y -> xb
  // FFN1: gelu(y@W1) -> tb bf16
  bgemm<<<dim3(50, 16, 4), 256, 0, stream>>>(xb, w1b, BSD, DH4, 1024, 256,
      (float*)0, 0, (const float*)0, 0, tb, T4, 1);
  // FFN2: t@W2 + h -> hbuf fp32
  bgemm<<<dim3(50, 4, 4), 256, 0, stream>>>(tb, w2b, T4, DH4, 256, 1024,
      hbuf, BSD, hbuf, BSD, (unsigned short*)0, 0, 0);
  combine_kernel<<<800, 256, 0, stream>>>(gates, hbuf, out);
}

// Round 5
// 441.216 us; speedup vs baseline: 2.0020x; 1.1157x over previous
//
#include <hip/hip_runtime.h>
#include <hip/hip_bf16.h>
#include <math.h>

#define K_ 4
#define B_ 64
#define S_ 50
#define D_ 256
#define V_ 40000
#define H_ 4
#define DH_ 64
#define NEG_ (-1e9f)
#define SCALE_ 0.125f

typedef __attribute__((ext_vector_type(8))) __bf16 bf16x8v;
typedef __attribute__((ext_vector_type(4))) float f32x4v;

// ---------- helpers ----------
__device__ __forceinline__ float wred_sum(float v) {
#pragma unroll
  for (int off = 32; off > 0; off >>= 1) v += __shfl_xor(v, off, 64);
  return v;
}
__device__ __forceinline__ float wred_max(float v) {
#pragma unroll
  for (int off = 32; off > 0; off >>= 1) v = fmaxf(v, __shfl_xor(v, off, 64));
  return v;
}
__device__ __forceinline__ float softplusf(float x) {
  return (x > 20.f) ? x : log1pf(expf(x));
}
__device__ __forceinline__ float geluf(float x) {
  const float c = 0.7978845608028654f;  // sqrt(2/pi)
  float x3 = x * x * x;
  return 0.5f * x * (1.f + tanhf(c * (x + 0.044715f * x3)));
}
__device__ __forceinline__ float bf2f(unsigned int u) {
  return __uint_as_float(u << 16);
}
__device__ __forceinline__ unsigned short f2bf(float f) {
  unsigned u = __float_as_uint(f);
  return (unsigned short)((u + 0x7fffu + ((u >> 16) & 1u)) >> 16);
}
__device__ __forceinline__ void unp8(uint4 a, float* d) {
  d[0] = bf2f(a.x & 0xffffu); d[1] = bf2f(a.x >> 16);
  d[2] = bf2f(a.y & 0xffffu); d[3] = bf2f(a.y >> 16);
  d[4] = bf2f(a.z & 0xffffu); d[5] = bf2f(a.z >> 16);
  d[6] = bf2f(a.w & 0xffffu); d[7] = bf2f(a.w >> 16);
}
__device__ __forceinline__ bf16x8v cvt8(float4 a, float4 b) {
  bf16x8v r;
  r[0] = (__bf16)a.x; r[1] = (__bf16)a.y; r[2] = (__bf16)a.z; r[3] = (__bf16)a.w;
  r[4] = (__bf16)b.x; r[5] = (__bf16)b.y; r[6] = (__bf16)b.z; r[7] = (__bf16)b.w;
  return r;
}

// ---------- weight cast fp32 -> bf16, TRANSPOSED to [N][Kd] per key ----------
// wqkvT [K][768][256] (q|k|v stacked in N), woT [K][256][256],
// w1T [K][1024][256], w2T [K][256][1024]
__global__ __launch_bounds__(256) void cast_weights(
    const float* __restrict__ wq, const float* __restrict__ wk,
    const float* __restrict__ wv, const float* __restrict__ wo,
    const float* __restrict__ w1, const float* __restrict__ w2,
    unsigned short* __restrict__ wqkvT, unsigned short* __restrict__ woT,
    unsigned short* __restrict__ w1T, unsigned short* __restrict__ w2T) {
  long i4 = ((long)blockIdx.x * 256 + threadIdx.x) * 4;
  if (i4 < 786432) {  // Wq/Wk/Wv -> wqkvT[k][sect*256+n][d]
    int sect = (int)(i4 / 262144);  // 0=q 1=k 2=v
    long e = i4 - (long)sect * 262144;
    const float* src = (sect == 0) ? wq : (sect == 1) ? wk : wv;
    int k = (int)(e >> 16), rem = (int)(e & 65535);
    int d = rem >> 8, n = rem & 255;
    float4 v = *(const float4*)(src + e);
    unsigned short* base = wqkvT + ((long)k * 768 + sect * 256 + n) * 256 + d;
    base[0] = f2bf(v.x); base[256] = f2bf(v.y);
    base[512] = f2bf(v.z); base[768] = f2bf(v.w);
    return;
  }
  if (i4 < 1048576) {  // Wo [K][256][256] -> woT[k][n][d]
    long e = i4 - 786432;
    int k = (int)(e >> 16), rem = (int)(e & 65535);
    int d = rem >> 8, n = rem & 255;
    float4 v = *(const float4*)(wo + e);
    unsigned short* base = woT + ((long)k * 256 + n) * 256 + d;
    base[0] = f2bf(v.x); base[256] = f2bf(v.y);
    base[512] = f2bf(v.z); base[768] = f2bf(v.w);
    return;
  }
  if (i4 < 2097152) {  // W1 [K][256][1024] -> w1T[k][n][d], n<1024,d<256
    long e = i4 - 1048576;
    int k = (int)(e >> 18), rem = (int)(e & 262143);
    int d = rem >> 10, n = rem & 1023;
    float4 v = *(const float4*)(w1 + e);
    unsigned short* base = w1T + ((long)k * 1024 + n) * 256 + d;
    base[0] = f2bf(v.x); base[256] = f2bf(v.y);
    base[512] = f2bf(v.z); base[768] = f2bf(v.w);
    return;
  }
  {  // W2 [K][1024][256] -> w2T[k][n][d], n<256,d<1024
    long e = i4 - 2097152;
    int k = (int)(e >> 18), rem = (int)(e & 262143);
    int d = rem >> 8, n = rem & 255;
    float4 v = *(const float4*)(w2 + e);
    unsigned short* base = w2T + ((long)k * 256 + n) * 1024 + d;
    base[0] = f2bf(v.x); base[1024] = f2bf(v.y);
    base[2048] = f2bf(v.z); base[3072] = f2bf(v.w);
  }
}

// ---------- gating ----------
__global__ __launch_bounds__(256) void gate_kernel(
    const int* __restrict__ ids, const float* __restrict__ emb,
    const float* __restrict__ Wg, const float* __restrict__ Wn,
    const float* __restrict__ eps, float* __restrict__ gates) {
  int w = threadIdx.x >> 6, lane = threadIdx.x & 63;
  int item = blockIdx.x * 4 + w;  // b*S+s
  int b = item / S_, s = item % S_;
  int d0 = lane * 4;
  float4 hs = make_float4(0.f, 0.f, 0.f, 0.f);
#pragma unroll
  for (int k = 0; k < K_; ++k) {
    int id = ids[(k * B_ + b) * S_ + s];
    const float4 e = *(const float4*)(emb + ((long)k * V_ + id) * D_ + d0);
    hs.x += e.x; hs.y += e.y; hs.z += e.z; hs.w += e.w;
  }
  hs.x *= 0.25f; hs.y *= 0.25f; hs.z *= 0.25f; hs.w *= 0.25f;
  float logit[4];
#pragma unroll
  for (int j = 0; j < K_; ++j) {
    float pg = hs.x * Wg[(d0 + 0) * K_ + j] + hs.y * Wg[(d0 + 1) * K_ + j] +
               hs.z * Wg[(d0 + 2) * K_ + j] + hs.w * Wg[(d0 + 3) * K_ + j];
    float pn = hs.x * Wn[(d0 + 0) * K_ + j] + hs.y * Wn[(d0 + 1) * K_ + j] +
               hs.z * Wn[(d0 + 2) * K_ + j] + hs.w * Wn[(d0 + 3) * K_ + j];
    pg = wred_sum(pg);
    pn = wred_sum(pn);
    logit[j] = pg + softplusf(pn) * eps[item * K_ + j];
  }
  if (lane == 0) {
    int i0 = 0; float v0 = logit[0];
    for (int j = 1; j < K_; ++j) if (logit[j] > v0) { v0 = logit[j]; i0 = j; }
    int i1 = -1; float v1 = 0.f;
    for (int j = 0; j < K_; ++j)
      if (j != i0 && (i1 < 0 || logit[j] > v1)) { v1 = logit[j]; i1 = j; }
    float w0 = 1.f / (1.f + expf(v1 - v0));
    float w1 = 1.f - w0;
#pragma unroll
    for (int j = 0; j < K_; ++j)
      gates[item * K_ + j] = (j == i0) ? w0 : ((j == i1) ? w1 : 0.f);
  }
}

// ---------- local aggregator via MFMA (round-4 kernel, kept) ----------
__global__ __launch_bounds__(256) void local_agg4(
    const int* __restrict__ items, const int* __restrict__ adj,
    const float* __restrict__ emb, const float* __restrict__ agg_a,
    float* __restrict__ h_raw) {
  __shared__ __bf16 hgb[64][264];
  __shared__ float e_f[50][68];
  __shared__ __bf16 alp[64][72];
  __shared__ unsigned char adj_s[64][64];
  __shared__ __bf16 a_sb[4][264];
  int kb = blockIdx.x;
  int k = kb >> 6, b = kb & 63;
  int t = threadIdx.x;
  for (int c = t; c < 2048; c += 256) {
    int row = c >> 5, c8 = (c & 31) * 8;
    bf16x8v val;
    if (row < S_) {
      int g = items[kb * S_ + row];
      const float* src = emb + ((long)k * V_ + g) * D_ + c8;
      val = cvt8(*(const float4*)src, *(const float4*)(src + 4));
    } else {
#pragma unroll
      for (int e = 0; e < 8; ++e) val[e] = (__bf16)0.f;
    }
    *(bf16x8v*)&hgb[row][c8] = val;
  }
  if (t < 128) {
    int row = t >> 5, c8 = (t & 31) * 8;
    const float* src = agg_a + ((long)k * 4 + row) * D_ + c8;
    *(bf16x8v*)&a_sb[row][c8] = cvt8(*(const float4*)src, *(const float4*)(src + 4));
  }
  for (int c = t; c < 4096; c += 256) {
    int i = c >> 6, j = c & 63;
    adj_s[i][j] = (i < S_ && j < S_)
                      ? (unsigned char)adj[((long)b * S_ + i) * S_ + j] : 0;
  }
  __syncthreads();
  int w = t >> 6, lane = t & 63;
  int m16 = lane & 15, quad = lane >> 4;
  float e_sel[4][4];
#pragma unroll
  for (int nt = 0; nt < 4; ++nt)
#pragma unroll
    for (int rg = 0; rg < 4; ++rg) e_sel[nt][rg] = NEG_;
#pragma unroll
  for (int r = 0; r < 4; ++r) {
    f32x4v acc[4];
#pragma unroll
    for (int nt = 0; nt < 4; ++nt) acc[nt] = (f32x4v){0.f, 0.f, 0.f, 0.f};
#pragma unroll
    for (int k0 = 0; k0 < 8; ++k0) {
      int kc = k0 * 32 + quad * 8;
      bf16x8v hr = *(const bf16x8v*)&hgb[w * 16 + m16][kc];
      bf16x8v ar = *(const bf16x8v*)&a_sb[r][kc];
      bf16x8v af;
#pragma unroll
      for (int e = 0; e < 8; ++e) af[e] = (__bf16)((float)hr[e] * (float)ar[e]);
#pragma unroll
      for (int nt = 0; nt < 4; ++nt) {
        bf16x8v bf = *(const bf16x8v*)&hgb[nt * 16 + m16][kc];
        acc[nt] = __builtin_amdgcn_mfma_f32_16x16x32_bf16(af, bf, acc[nt], 0, 0, 0);
      }
    }
#pragma unroll
    for (int nt = 0; nt < 4; ++nt)
#pragma unroll
      for (int rg = 0; rg < 4; ++rg) {
        int i = w * 16 + quad * 4 + rg, j = nt * 16 + m16;
        if (adj_s[i][j] == r + 1) {
          float v = acc[nt][rg];
          e_sel[nt][rg] = (v >= 0.f) ? v : 0.2f * v;
        }
      }
  }
#pragma unroll
  for (int nt = 0; nt < 4; ++nt)
#pragma unroll
    for (int rg = 0; rg < 4; ++rg) {
      int i = w * 16 + quad * 4 + rg;
      if (i < S_) e_f[i][nt * 16 + m16] = e_sel[nt][rg];
    }
  __syncthreads();
  for (int i = w; i < S_; i += 4) {
    float val = (lane < S_) ? e_f[i][lane] : -INFINITY;
    float m = wred_max(val);
    float p = expf(val - m);
    float ssum = wred_sum(p);
    alp[i][lane] = (__bf16)(p / ssum);
  }
  __syncthreads();
#pragma unroll 4
  for (int nt = 0; nt < 16; ++nt) {
    f32x4v acc = (f32x4v){0.f, 0.f, 0.f, 0.f};
#pragma unroll
    for (int k0 = 0; k0 < 2; ++k0) {
      int jb = k0 * 32 + quad * 8;
      bf16x8v af = *(const bf16x8v*)&alp[w * 16 + m16][jb];
      bf16x8v bf;
#pragma unroll
      for (int tt = 0; tt < 8; ++tt) bf[tt] = hgb[jb + tt][nt * 16 + m16];
      acc = __builtin_amdgcn_mfma_f32_16x16x32_bf16(af, bf, acc, 0, 0, 0);
    }
#pragma unroll
    for (int rg = 0; rg < 4; ++rg) {
      int i = w * 16 + quad * 4 + rg;
      if (i < S_)
        h_raw[((long)kb * S_ + i) * D_ + nt * 16 + m16] = acc[rg];
    }
  }
}

// ---------- alias gather + LN1 ----------
__global__ __launch_bounds__(256) void gather_ln(
    const float* __restrict__ h_raw, const int* __restrict__ alias_,
    float* __restrict__ hbuf, unsigned short* __restrict__ xb,
    const float* __restrict__ g, const float* __restrict__ bta) {
  int kb = blockIdx.x;
  int k = kb >> 6, b = kb & 63;
  int w = threadIdx.x >> 6, lane = threadIdx.x & 63;
  for (int s = w; s < S_; s += 4) {
    int src = alias_[b * S_ + s];
    const float4 v = *(const float4*)(h_raw + ((long)kb * S_ + src) * D_ + lane * 4);
    long off = ((long)kb * S_ + s) * D_ + lane * 4;
    *(float4*)(hbuf + off) = v;
    float sum = wred_sum(v.x + v.y + v.z + v.w);
    float sq = wred_sum(v.x * v.x + v.y * v.y + v.z * v.z + v.w * v.w);
    float mean = sum * (1.f / D_);
    float var = sq * (1.f / D_) - mean * mean;
    float rs = rsqrtf(var + 1e-5f);
    const float4 gv = *(const float4*)(g + k * D_ + lane * 4);
    const float4 bv = *(const float4*)(bta + k * D_ + lane * 4);
    ushort4 o;
    o.x = f2bf((v.x - mean) * rs * gv.x + bv.x);
    o.y = f2bf((v.y - mean) * rs * gv.y + bv.y);
    o.z = f2bf((v.z - mean) * rs * gv.z + bv.z);
    o.w = f2bf((v.w - mean) * rs * gv.w + bv.w);
    *(ushort4*)(xb + off) = o;
  }
}

// ---------- layernorm -> bf16 out ----------
__global__ __launch_bounds__(256) void ln_bf16(
    const float* __restrict__ x, unsigned short* __restrict__ y,
    const float* __restrict__ g, const float* __restrict__ bta) {
  int w = threadIdx.x >> 6, lane = threadIdx.x & 63;
  long row = (long)blockIdx.x * 4 + w;
  int k = (int)(row / (B_ * S_));
  const float4 v = *(const float4*)(x + row * D_ + lane * 4);
  float sum = wred_sum(v.x + v.y + v.z + v.w);
  float sq = wred_sum(v.x * v.x + v.y * v.y + v.z * v.z + v.w * v.w);
  float mean = sum * (1.f / D_);
  float var = sq * (1.f / D_) - mean * mean;
  float rs = rsqrtf(var + 1e-5f);
  const float4 gv = *(const float4*)(g + k * D_ + lane * 4);
  const float4 bv = *(const float4*)(bta + k * D_ + lane * 4);
  ushort4 o;
  o.x = f2bf((v.x - mean) * rs * gv.x + bv.x);
  o.y = f2bf((v.y - mean) * rs * gv.y + bv.y);
  o.z = f2bf((v.z - mean) * rs * gv.z + bv.z);
  o.w = f2bf((v.w - mean) * rs * gv.w + bv.w);
  *(ushort4*)(y + row * D_ + lane * 4) = o;
}

// ---------- bf16 MFMA GEMM v2: 64x64 tile, BK=64, Bt=[N][Kd], prefetch ----------
__global__ __launch_bounds__(256) void bgemm2(
    const unsigned short* __restrict__ A, const unsigned short* __restrict__ Bt,
    long strideA, long strideBt, int N, int Kd,
    float* __restrict__ Cf, long strideCf,
    const float* __restrict__ R, long strideR,
    unsigned short* __restrict__ Cb, long strideCb, int act) {
  __shared__ unsigned short sA[64][72];  // [m][k], row 144 B -> frag reads 2-way (free)
  __shared__ unsigned short sB[64][72];  // [n][k]
  int z = blockIdx.z;
  A += (long)z * strideA;
  Bt += (long)z * strideBt;
  int t = threadIdx.x, w = t >> 6, lane = t & 63;
  int row0 = blockIdx.x * 64, col0 = blockIdx.y * 64;
  int m16 = lane & 15, quad = lane >> 4;
  f32x4v acc[4];
#pragma unroll
  for (int nt = 0; nt < 4; ++nt) acc[nt] = (f32x4v){0.f, 0.f, 0.f, 0.f};
  // staging map: thread t covers row (t>>2), k-cols (t&3)*16 + {0..7, 8..15}
  int sr = t >> 2, sc = (t & 3) * 16;
  const unsigned short* pa = A + (long)(row0 + sr) * Kd + sc;
  const unsigned short* pb = Bt + (long)(col0 + sr) * Kd + sc;
  uint4 a0 = *(const uint4*)(pa);
  uint4 a1 = *(const uint4*)(pa + 8);
  uint4 b0 = *(const uint4*)(pb);
  uint4 b1 = *(const uint4*)(pb + 8);
  for (int k0 = 0; k0 < Kd; k0 += 64) {
    __syncthreads();  // protect previous iteration's LDS reads
    *(uint4*)&sA[sr][sc] = a0;
    *(uint4*)&sA[sr][sc + 8] = a1;
    *(uint4*)&sB[sr][sc] = b0;
    *(uint4*)&sB[sr][sc + 8] = b1;
    // prefetch next K-slab while LDS settles / MFMA runs
    if (k0 + 64 < Kd) {
      a0 = *(const uint4*)(pa + k0 + 64);
      a1 = *(const uint4*)(pa + k0 + 72);
      b0 = *(const uint4*)(pb + k0 + 64);
      b1 = *(const uint4*)(pb + k0 + 72);
    }
    __syncthreads();
#pragma unroll
    for (int half = 0; half < 2; ++half) {
      int kg = half * 32 + quad * 8;
      bf16x8v af = *(const bf16x8v*)&sA[w * 16 + m16][kg];
#pragma unroll
      for (int nt = 0; nt < 4; ++nt) {
        bf16x8v bf = *(const bf16x8v*)&sB[nt * 16 + m16][kg];
        acc[nt] = __builtin_amdgcn_mfma_f32_16x16x32_bf16(af, bf, acc[nt], 0, 0, 0);
      }
    }
  }
  // epilogue: C/D layout col=lane&15, row=quad*4+reg [m89/m91]
  int rbase = row0 + w * 16 + quad * 4;
  int cb = m16;
#pragma unroll
  for (int nt = 0; nt < 4; ++nt) {
#pragma unroll
    for (int i2 = 0; i2 < 4; ++i2) {
      long off = (long)(rbase + i2) * N + col0 + nt * 16 + cb;
      float vv = acc[nt][i2];
      if (R) vv += R[(long)z * strideR + off];
      if (act == 1) vv = geluf(vv);
      if (Cf) Cf[(long)z * strideCf + off] = vv;
      if (Cb) Cb[(long)z * strideCb + off] = f2bf(vv);
    }
  }
}

// ---------- causal MHA: block per (k,b,head); packed qkv [K*B*S][768] ----------
__global__ __launch_bounds__(256) void attn_kernel(
    const unsigned short* __restrict__ qkv, unsigned short* __restrict__ o) {
  __shared__ float qs[S_][65], ks[S_][65], vs[S_][65];
  int idx = blockIdx.x;
  int h = idx & 3;
  int kb = idx >> 2;
  long base = (long)kb * S_ * 768;
  int t = threadIdx.x;
  for (int f = t; f < S_ * 8; f += 256) {
    int row = f >> 3, c8 = (f & 7) * 8;
    long g = base + (long)row * 768 + h * DH_ + c8;
    unp8(*(const uint4*)(qkv + g), &qs[row][c8]);
    unp8(*(const uint4*)(qkv + g + 256), &ks[row][c8]);
    unp8(*(const uint4*)(qkv + g + 512), &vs[row][c8]);
  }
  __syncthreads();
  int w = t >> 6, lane = t & 63;
  for (int i = w; i < S_; i += 4) {
    int jj = (lane < S_) ? lane : 0;
    float dot = 0.f;
#pragma unroll
    for (int d = 0; d < DH_; ++d) dot = fmaf(qs[i][d], ks[jj][d], dot);
    float val = (lane <= i) ? dot * SCALE_ : ((lane < S_) ? NEG_ : -INFINITY);
    float m = wred_max(val);
    float p = expf(val - m);
    float ssum = wred_sum(p);
    float pr = p / ssum;
    float acc = 0.f;
    for (int j = 0; j <= i; ++j)
      acc = fmaf(__shfl(pr, j, 64), vs[j][lane], acc);
    o[((long)kb * S_ + i) * D_ + h * DH_ + lane] = f2bf(acc);
  }
}

// ---------- gated combine ----------
__global__ __launch_bounds__(256) void combine_kernel(
    const float* __restrict__ gates, const float* __restrict__ h,
    float* __restrict__ out) {
  int w = threadIdx.x >> 6, lane = threadIdx.x & 63;
  int item = blockIdx.x * 4 + w;
  float g0 = gates[item * 4 + 0], g1 = gates[item * 4 + 1];
  float g2 = gates[item * 4 + 2], g3 = gates[item * 4 + 3];
  long off = (long)item * D_ + lane * 4;
  const long PK = (long)B_ * S_ * D_;
  float4 a = *(const float4*)(h + off);
  float4 b = *(const float4*)(h + PK + off);
  float4 c = *(const float4*)(h + 2 * PK + off);
  float4 d = *(const float4*)(h + 3 * PK + off);
  float4 o;
  o.x = g0 * a.x + g1 * b.x + g2 * c.x + g3 * d.x;
  o.y = g0 * a.y + g1 * b.y + g2 * c.y + g3 * d.y;
  o.z = g0 * a.z + g1 * b.z + g2 * c.z + g3 * d.z;
  o.w = g0 * a.w + g1 * b.w + g2 * c.w + g3 * d.w;
  *(float4*)(out + off) = o;
}

extern "C" void kernel_launch(void* const* d_in, const int* in_sizes, int n_in,
                              void* d_out, int out_size, void* d_ws,
                              size_t ws_size, hipStream_t stream) {
  const int* ids = (const int*)d_in[0];
  const int* items = (const int*)d_in[1];
  const int* adj = (const int*)d_in[2];
  const int* alias = (const int*)d_in[3];
  const float* eps = (const float*)d_in[4];
  const float* emb = (const float*)d_in[5];
  const float* agg_a = (const float*)d_in[6];
  const float* Wq = (const float*)d_in[7];
  const float* Wk = (const float*)d_in[8];
  const float* Wv = (const float*)d_in[9];
  const float* Wo = (const float*)d_in[10];
  const float* ln1g = (const float*)d_in[11];
  const float* ln1b = (const float*)d_in[12];
  const float* W1 = (const float*)d_in[13];
  const float* W2 = (const float*)d_in[14];
  const float* ln2g = (const float*)d_in[15];
  const float* ln2b = (const float*)d_in[16];
  const float* Wg = (const float*)d_in[17];
  const float* Wn = (const float*)d_in[18];
  float* out = (float*)d_out;

  const long BSD = (long)B_ * S_ * D_;  // 819200
  float* ws = (float*)d_ws;
  float* gates = ws;                    // 16384 fp32
  float* hbuf = ws + 16384;             // [K,B,S,D] fp32 residual stream
  unsigned short* ub = (unsigned short*)(ws + 16384 + 4 * BSD);
  unsigned short* xb = ub;              // x / attn-o / y slot [K,B,S,D] bf16
  unsigned short* qkvb = ub + 3276800;  // [K,B*S,768] = 9830400
  unsigned short* tb = qkvb;            // FFN hidden [K,B*S,1024] = 13107200
  float* h_raw = (float*)qkvb;          // pre-alias h_local (dead before QKV)
  unsigned short* wqkvT = ub + 16384000;   // 786432
  unsigned short* woT = wqkvT + 786432;    // 262144
  unsigned short* w1T = woT + 262144;      // 1048576
  unsigned short* w2T = w1T + 1048576;     // 1048576

  const long T4 = 3276800;

  cast_weights<<<3072, 256, 0, stream>>>(Wq, Wk, Wv, Wo, W1, W2,
                                         wqkvT, woT, w1T, w2T);
  gate_kernel<<<800, 256, 0, stream>>>(ids, emb, Wg, Wn, eps, gates);
  local_agg4<<<256, 256, 0, stream>>>(items, adj, emb, agg_a, h_raw);
  gather_ln<<<256, 256, 0, stream>>>(h_raw, alias, hbuf, xb, ln1g, ln1b);
  // fused QKV projection -> qkvb (h_raw dead from here)
  bgemm2<<<dim3(50, 12, 4), 256, 0, stream>>>(xb, wqkvT, BSD, 196608, 768, 256,
      (float*)0, 0, (const float*)0, 0, qkvb, 2457600, 0);
  attn_kernel<<<K_ * B_ * H_, 256, 0, stream>>>(qkvb, xb);  // o -> xb
  // O projection + residual -> hbuf fp32
  bgemm2<<<dim3(50, 4, 4), 256, 0, stream>>>(xb, woT, BSD, 65536, 256, 256,
      hbuf, BSD, hbuf, BSD, (unsigned short*)0, 0, 0);
  ln_bf16<<<3200, 256, 0, stream>>>(hbuf, xb, ln2g, ln2b);  // y -> xb
  // FFN1: gelu(y@W1) -> tb bf16
  bgemm2<<<dim3(50, 16, 4), 256, 0, stream>>>(xb, w1T, BSD, 262144, 1024, 256,
      (float*)0, 0, (const float*)0, 0, tb, T4, 1);
  // FFN2: t@W2 + h -> hbuf fp32
  bgemm2<<<dim3(50, 4, 4), 256, 0, stream>>>(tb, w2T, T4, 262144, 256, 1024,
      hbuf, BSD, hbuf, BSD, (unsigned short*)0, 0, 0);
  combine_kernel<<<800, 256, 0, stream>>>(gates, hbuf, out);
}